// Round 1
// baseline (2479.726 us; speedup 1.0000x reference)
//
#include <hip/hip_runtime.h>
#include <hip/hip_bf16.h>

// TimeLSTM: B=2048, T=256, IN=65 (1 time-delta + 64 features), H=256, gates=1024.
//
// Design (round 1):
//  - prep kernel: swizzle [W_ih | W_hh] (fp32) -> bf16 MFMA B-fragment order in d_ws.
//    Fragment layout for v_mfma_f32_16x16x32_bf16 B operand: lane L holds
//    W[n = base_n + (L&15)][k = base_k + (L>>4)*8 + j], j=0..7  (16B per lane).
//  - scan kernel: 128 persistent blocks x 256 threads; each block owns 16 batch rows,
//    iterates t=0..255. Per step: stage x_t (bf16) + h (bf16) as A in LDS,
//    GEMM 16x1024x320 via 16x16x32 bf16 MFMA (4 waves x 16 n-tiles x 10 k-steps),
//    lane-local LSTM epilogue (fp32 c-state in registers), h written back to LDS.
//  - W k-tiles 0..1 (== W_ih, 128KB) LDS-resident; k-tiles 2..9 (W_hh, 512KB)
//    streamed from L2 each step (per-CU L2 rate is the expected bottleneck).
//  - N-assignment: wave w, tile nt=g*4+jt -> n = g*256 + w*64 + jt*16 + (lane&15),
//    so each lane holds i,f,g,o for the same h-column -> gate fusion is lane-local.
//  - C/D layout (m89-verified): col = lane&15, row = (lane>>4)*4 + reg.

typedef __bf16 v8bf __attribute__((ext_vector_type(8)));
typedef __bf16 v4bf __attribute__((ext_vector_type(4)));
typedef float f32x4 __attribute__((ext_vector_type(4)));

#define B_SZ 2048
#define T_SZ 256
#define IN_SZ 65
#define H_SZ 256
#define NKT 10          // 320 / 32 k-steps
#define RES_KT 2        // k-tiles resident in LDS (= W_ih exactly)
#define MBLK 16
#define NBLOCKS (B_SZ / MBLK)   // 128

#define WRES_BYTES (RES_KT * 64 * 1024)       // 131072
#define A_STRIDE 328                           // 320 + 8 bf16 pad (16B-aligned rows, 2-way-free banks)
#define A_BYTES (16 * A_STRIDE * 2)            // 10496
#define SMEM_TOTAL (WRES_BYTES + A_BYTES + 64 + 64)

__device__ __forceinline__ float fsig(float xv) {
    return __builtin_amdgcn_rcpf(1.f + __expf(-xv));
}
__device__ __forceinline__ float ftanh(float xv) {
    return fmaf(2.f, fsig(2.f * xv), -1.f);
}

// ---------------- prep: swizzle W into MFMA B-fragment order (bf16) ----------------
// 640 fragments (kt 0..9, w 0..3, nt 0..15), 1KB each: total 640KB in d_ws.
__global__ void prep_w(const float* __restrict__ W_ih, const float* __restrict__ W_hh,
                       __bf16* __restrict__ wsz) {
    int gtid = blockIdx.x * 256 + threadIdx.x;   // 0..40959
    int lane = gtid & 63;
    int frag = gtid >> 6;                        // 0..639
    int kt = frag >> 6;
    int w  = (frag >> 4) & 3;
    int nt = frag & 15;
    int g = nt >> 2, jt = nt & 3;
    int n  = g * 256 + w * 64 + jt * 16 + (lane & 15);
    int k0 = kt * 32 + ((lane >> 4) << 3);
    v8bf v;
#pragma unroll
    for (int j = 0; j < 8; ++j) {
        int k = k0 + j;
        float f = (k < 64) ? W_ih[n * 64 + k] : W_hh[n * 256 + (k - 64)];
        v[j] = (__bf16)f;
    }
    *reinterpret_cast<v8bf*>(wsz + (size_t)frag * 512 + lane * 8) = v;
}

// ---------------- fused persistent scan ----------------
__global__ __launch_bounds__(256, 1) void tlstm_scan(
    const float* __restrict__ x, const __bf16* __restrict__ wsz,
    const float* __restrict__ b_ih, const float* __restrict__ b_hh,
    const float* __restrict__ Wt, const float* __restrict__ bt,
    const float* __restrict__ Wf, const float* __restrict__ bfp,
    float* __restrict__ out) {
    extern __shared__ char smem[];
    __bf16* Wres  = reinterpret_cast<__bf16*>(smem);                       // 128KB
    __bf16* A     = reinterpret_cast<__bf16*>(smem + WRES_BYTES);          // 16 x 328 bf16
    float* td_lds = reinterpret_cast<float*>(smem + WRES_BYTES + A_BYTES); // 16 f32
    float* out_acc = reinterpret_cast<float*>(smem + WRES_BYTES + A_BYTES + 64);

    const int tid  = threadIdx.x;
    const int lane = tid & 63;
    const int w    = tid >> 6;
    const int l15  = lane & 15;
    const int lhi  = lane >> 4;
    const int b0   = blockIdx.x * MBLK;

    // one-time: copy resident W k-tiles (frag 0..127) into LDS
    {
        const uint4* src = reinterpret_cast<const uint4*>(wsz);
        uint4* dst = reinterpret_cast<uint4*>(Wres);
#pragma unroll
        for (int i = 0; i < 32; ++i) dst[tid + i * 256] = src[tid + i * 256];
    }
    // zero A (h region must start at 0; x region overwritten every step)
    for (int i = tid; i < 16 * A_STRIDE; i += 256) A[i] = (__bf16)0.f;
    if (tid < 16) out_acc[tid] = 0.f;

    // per-lane constants: this lane's 4 columns (jt=0..3) at col = w*64 + jt*16 + l15
    float bias[4][4], wt_r[4], bt_r[4], wf_r[4];
#pragma unroll
    for (int jt = 0; jt < 4; ++jt) {
        int col = w * 64 + jt * 16 + l15;
#pragma unroll
        for (int g = 0; g < 4; ++g) bias[g][jt] = b_ih[g * 256 + col] + b_hh[g * 256 + col];
        wt_r[jt] = Wt[col];
        bt_r[jt] = bt[col];
        wf_r[jt] = Wf[col];
    }

    float cst[4][4];   // fp32 cell state: [jt][reg]
#pragma unroll
    for (int jt = 0; jt < 4; ++jt)
#pragma unroll
        for (int r = 0; r < 4; ++r) cst[jt][r] = 0.f;
    float outp[4] = {0.f, 0.f, 0.f, 0.f};

    const int xr = tid >> 4;   // row this thread stages (0..15)
    const int xc = tid & 15;   // 4-feature chunk (0..15)

    __syncthreads();           // Wres copy + A zero visible

    for (int t = 0; t < T_SZ; ++t) {
        // ---- stage x_t: 16 rows x 64 features -> A[:, 0:64) as bf16; time-delta -> td_lds
        {
            const float* xrow = x + ((size_t)(b0 + xr) * T_SZ + t) * IN_SZ;
            float f0 = xrow[1 + xc * 4 + 0];
            float f1 = xrow[1 + xc * 4 + 1];
            float f2 = xrow[1 + xc * 4 + 2];
            float f3 = xrow[1 + xc * 4 + 3];
            v4bf vv;
            vv[0] = (__bf16)f0; vv[1] = (__bf16)f1; vv[2] = (__bf16)f2; vv[3] = (__bf16)f3;
            *reinterpret_cast<v4bf*>(A + xr * A_STRIDE + xc * 4) = vv;
            if (xc == 0) td_lds[xr] = xrow[0];
        }
        __syncthreads();   // barrier A: x_t + h(t-1) ready in LDS

        // ---- A fragments: lane holds A[m=l15][k = kt*32 + lhi*8 + 0..7]
        v8bf a[NKT];
#pragma unroll
        for (int kt = 0; kt < NKT; ++kt)
            a[kt] = *reinterpret_cast<const v8bf*>(A + l15 * A_STRIDE + kt * 32 + lhi * 8);

        float tdv[4];
#pragma unroll
        for (int r = 0; r < 4; ++r) tdv[r] = td_lds[lhi * 4 + r];

        f32x4 acc[16];
#pragma unroll
        for (int i = 0; i < 16; ++i) acc[i] = (f32x4){0.f, 0.f, 0.f, 0.f};

        // ---- GEMM: kt 0..1 from LDS-resident W_ih, kt 2..9 streamed from L2
#pragma unroll
        for (int kt = 0; kt < NKT; ++kt) {
#pragma unroll
            for (int nt = 0; nt < 16; ++nt) {
                int frag = (kt * 4 + w) * 16 + nt;
                v8bf b;
                if (kt < RES_KT)
                    b = *reinterpret_cast<const v8bf*>(Wres + (size_t)frag * 512 + lane * 8);
                else
                    b = *reinterpret_cast<const v8bf*>(wsz + (size_t)frag * 512 + lane * 8);
                acc[nt] = __builtin_amdgcn_mfma_f32_16x16x32_bf16(a[kt], b, acc[nt], 0, 0, 0);
            }
        }
        __syncthreads();   // barrier B: all A reads done before h is overwritten

        // ---- lane-local LSTM epilogue (all 4 gates for this lane's columns)
        const bool last = (t == T_SZ - 1);
#pragma unroll
        for (int jt = 0; jt < 4; ++jt) {
#pragma unroll
            for (int r = 0; r < 4; ++r) {
                float pi = acc[0 * 4 + jt][r] + bias[0][jt];
                float pf = acc[1 * 4 + jt][r] + bias[1][jt];
                float pg = acc[2 * 4 + jt][r] + bias[2][jt];
                float po = acc[3 * 4 + jt][r] + bias[3][jt];
                float d  = fsig(fmaf(tdv[r], wt_r[jt], bt_r[jt]));
                float c  = cst[jt][r] * d;                    // c *= decay
                c = fsig(pf) * c + fsig(pi) * ftanh(pg);      // c = f*c + i*g
                cst[jt][r] = c;
                float h = fsig(po) * ftanh(c);                // h = o*tanh(c)
                int row = lhi * 4 + r;
                int col = w * 64 + jt * 16 + l15;
                A[row * A_STRIDE + 64 + col] = (__bf16)h;     // h -> A layout for next step
                if (last) outp[r] = fmaf(h, wf_r[jt], outp[r]);
            }
        }
    }

    // ---- output: out[b] = h_T . Wf + bf
#pragma unroll
    for (int r = 0; r < 4; ++r) atomicAdd(&out_acc[lhi * 4 + r], outp[r]);
    __syncthreads();
    if (tid < 16) out[b0 + tid] = out_acc[tid] + bfp[0];
}

extern "C" void kernel_launch(void* const* d_in, const int* in_sizes, int n_in,
                              void* d_out, int out_size, void* d_ws, size_t ws_size,
                              hipStream_t stream) {
    const float* x    = (const float*)d_in[0];
    const float* W_ih = (const float*)d_in[1];
    const float* W_hh = (const float*)d_in[2];
    const float* b_ih = (const float*)d_in[3];
    const float* b_hh = (const float*)d_in[4];
    const float* Wt   = (const float*)d_in[5];
    const float* bt   = (const float*)d_in[6];
    const float* Wf   = (const float*)d_in[7];
    const float* bfp  = (const float*)d_in[8];
    float* out  = (float*)d_out;
    __bf16* wsz = (__bf16*)d_ws;   // 640KB of swizzled bf16 W

    (void)in_sizes; (void)n_in; (void)out_size; (void)ws_size;

    // >64KB dynamic LDS needs the opt-in attribute (host-side call; graph-capture safe)
    hipFuncSetAttribute(reinterpret_cast<const void*>(tlstm_scan),
                        hipFuncAttributeMaxDynamicSharedMemorySize, SMEM_TOTAL);

    prep_w<<<dim3(160), dim3(256), 0, stream>>>(W_ih, W_hh, wsz);
    tlstm_scan<<<dim3(NBLOCKS), dim3(256), SMEM_TOTAL, stream>>>(
        x, wsz, b_ih, b_hh, Wt, bt, Wf, bfp, out);
}